// Round 12
// baseline (512.469 us; speedup 1.0000x reference)
//
#include <hip/hip_runtime.h>
#include <cstdint>
#include <cstddef>

#define S_LEN 2048
#define H_DIM 4096
#define NHEAD 32
#define HD    128
#define N_QKV 12288
#define INV_NORM 0.08838834764831845f  // 1/sqrt(128)

typedef __bf16 bf16_t;
typedef bf16_t bf16x8 __attribute__((ext_vector_type(8)));
typedef bf16_t bf16x4 __attribute__((ext_vector_type(4)));
typedef float  f32x4  __attribute__((ext_vector_type(4)));

static_assert(sizeof(bf16x8) == 16, "bf16x8 must be 16B");

__device__ __forceinline__ f32x4 mfma16(bf16x8 a, bf16x8 b, f32x4 c) {
  return __builtin_amdgcn_mfma_f32_16x16x32_bf16(a, b, c, 0, 0, 0);
}

// async global->LDS, 16B per lane. LDS dest must be wave-uniform base; HW adds lane*16.
typedef __attribute__((address_space(1))) void gas_void;
typedef __attribute__((address_space(3))) void las_void;
__device__ __forceinline__ void async16(const void* g, void* l) {
  __builtin_amdgcn_global_load_lds((const gas_void*)g,
                                   (las_void*)(uint32_t)(uintptr_t)l,
                                   16, 0, 0);
}

// 3-bit row XOR swizzle (G4): byte ^= (row&7)<<4.
// SWZ   : 128B rows (row = byte>>7) — GEMM tiles
// SWZ256: 256B rows (row = byte>>8) — attention K tiles (HD=128 bf16 rows)
// Both: involution, preserves 16B granules, spreads 16-lane column reads over 8 bank-quads.
#define SWZ(x)    ((x) ^ ((((x) >> 7) & 7) << 4))
#define SWZ256(x) ((x) ^ ((((x) >> 8) & 7) << 4))
#define VMCNT(n) asm volatile("s_waitcnt vmcnt(" #n ")" ::: "memory")
#define LGKM0()  asm volatile("s_waitcnt lgkmcnt(0)" ::: "memory")
#define SCHED0() __builtin_amdgcn_sched_barrier(0)
#define BARRIER() __builtin_amdgcn_s_barrier()

// ---------------- fp32 -> bf16 conversion: all three tensors in one launch ----------------
typedef float f32v4 __attribute__((ext_vector_type(4)));
#define NX4 ((S_LEN * H_DIM) / 4)
#define NQ4 ((N_QKV * H_DIM) / 4)
#define ND4 ((H_DIM * H_DIM) / 4)
__global__ void cvt_all(const float* __restrict__ x, const float* __restrict__ wq,
                        const float* __restrict__ wd,
                        bf16_t* __restrict__ xb, bf16_t* __restrict__ wqb,
                        bf16_t* __restrict__ wdb) {
  int i = blockIdx.x * 256 + threadIdx.x;
  const float* src; bf16_t* dst; int j;
  if (i < NX4) { src = x; dst = xb; j = i; }
  else if (i < NX4 + NQ4) { src = wq; dst = wqb; j = i - NX4; }
  else if (i < NX4 + NQ4 + ND4) { src = wd; dst = wdb; j = i - NX4 - NQ4; }
  else return;
  f32v4 v = ((const f32v4*)src)[j];
  bf16x4 r;
  r[0] = (bf16_t)v[0]; r[1] = (bf16_t)v[1]; r[2] = (bf16_t)v[2]; r[3] = (bf16_t)v[3];
  ((bf16x4*)dst)[j] = r;
}

// ============ GEMM: 128 x BN tile, BK=64, 2-phase, 2 BLOCKS/CU (TLP overlap) ============
// C = A(Mx4096) * B(Nx4096)^T. 256 threads = 4 waves (2M x 2N); wave tile 64 x BN/2,
// acc[4][BN/32] f32x4. LDS: A 2buf x 16KB + B 2buf x BN*128B  (BN=192 -> 80KB exactly
// -> 2 blocks/CU; BN=128 -> 64KB). The two co-resident blocks share no barrier, so
// one block's LDS-read phase overlaps the other's MFMA phase (m114 TLP co-schedule) —
// this attacks the measured wall = MFMA(1863) + LDS-port(1920) serialization of the
// single-block barrier-locked structure (r9/r11: both phases strictly added).
// Row-swizzled (SWZ) via inverse-swizzled global source + swizzled ds_read.
//   P1: read B(t) all + A(t) mi01; stage A(t+1) u0-3 (4KB each); MFMA mi=0,1
//   P2: read A(t) mi23;            stage B(t+2) u0..BU-1;        MFMA mi=2,3
// vmcnt FIFO ledger (induction, stage unit = 256thr x 16B = 4KB):
//   At P2(t) wait: outstanding = [B(t+1) x BU, A(t+1) x4, B(t+2) x BU] -> VMCNT(BU)
//   lands B(t+1)+A(t+1) (needed at P1(t+1)). t==NT-2 -> VMCNT(0); t==NT-1 -> none.
//   Prologue [B0 xBU, A0 x4, B1 xBU] -> VMCNT(BU).
// Race-freedom: frags consumed by MFMAs before each phase-end barrier => all LDS
// reads of a buffer retire before any wave issues the stage that overwrites it.
// MODE 0: QKV epilogue (scatter Q*INV_NORM / K / V per 128-col chunk)
// MODE 1: dense epilogue (fp32 out = acc + bias + residual)
template <int MODE, int BN>
__global__ __launch_bounds__(256, 2)
void gemm_pipe(const bf16_t* __restrict__ Ag,
               const bf16_t* __restrict__ Bg,
               const float* __restrict__ bias,
               const float* __restrict__ residual,
               bf16_t* __restrict__ q_out,
               bf16_t* __restrict__ k_out,
               bf16_t* __restrict__ v_out,
               float* __restrict__ f_out,
               int ncol)
{
  constexpr int NFRAG = BN / 32;      // B col-frags per wave (16 cols each)
  constexpr int BU    = BN / 32;      // B stage issues (4KB each) per K-tile
  constexpr int BBUF  = BN * 128;     // B bytes per buffer
  __shared__ __align__(16) char sm[32768 + 2 * BBUF];
  char* smA = sm;             // [buf][16384]
  char* smB = sm + 32768;     // [buf][BBUF]
  const int Kdim = H_DIM;
  const int NT = Kdim >> 6;   // 64 K-tiles

  const int tid = threadIdx.x, lane = tid & 63, w = tid >> 6;
  const int wm = w >> 1, wn = w & 1;
  const int lo = lane & 15, g = lane >> 4;

  // XCD-aware bijective swizzle (nwg % 8 == 0)
  const int nwg = gridDim.x * gridDim.y;
  const int bid = blockIdx.y * gridDim.x + blockIdx.x;
  const int cpx = nwg >> 3;
  const int sbid = (bid & 7) * cpx + (bid >> 3);
  const int brow = (sbid / ncol) << 7;
  const int bcol = (sbid % ncol) * BN;

  auto stageA = [&](int t, int u) {          // u = 0..3, 4KB each (32 rows)
    const int lin = u * 4096 + tid * 16;
    const int lg = SWZ(lin);
    const bf16_t* src = Ag + (size_t)(brow + (lg >> 7)) * Kdim + (t << 6) + ((lg & 127) >> 1);
    async16(src, smA + ((t & 1) * 16384 + u * 4096 + w * 1024));
  };
  auto stageB = [&](int t, int u) {          // u = 0..BU-1, 4KB each
    const int lin = u * 4096 + tid * 16;
    const int lg = SWZ(lin);
    const bf16_t* src = Bg + (size_t)(bcol + (lg >> 7)) * Kdim + (t << 6) + ((lg & 127) >> 1);
    async16(src, smB + ((t & 1) * BBUF + u * 4096 + w * 1024));
  };
  auto rdA = [&](int t, int mi, int ks) -> bf16x8 {
    const int lin = (wm * 64 + mi * 16 + lo) * 128 + ks * 64 + g * 16;
    return *(const bf16x8*)(smA + (t & 1) * 16384 + SWZ(lin));
  };
  auto rdB = [&](int t, int ni, int ks) -> bf16x8 {
    const int lin = (wn * (BN / 2) + ni * 16 + lo) * 128 + ks * 64 + g * 16;
    return *(const bf16x8*)(smB + (t & 1) * BBUF + SWZ(lin));
  };

  f32x4 acc[4][NFRAG] = {};
  bf16x8 bfrag[NFRAG][2];

  // ---- prologue: FIFO = [B0 xBU, A0 x4, B1 xBU] -> VMCNT(BU) lands B0+A0
#pragma unroll
  for (int u = 0; u < BU; ++u) stageB(0, u);
  stageA(0, 0); stageA(0, 1); stageA(0, 2); stageA(0, 3);
#pragma unroll
  for (int u = 0; u < BU; ++u) stageB(1, u);
  if constexpr (BU == 6) { VMCNT(6); } else { VMCNT(4); }
  SCHED0();
  BARRIER();

  for (int t = 0; t < NT; ++t) {
    bf16x8 afrag[2][2];
    // ---- P1: issue B(t) all + A(t) mi01 reads; stage A(t+1)
#pragma unroll
    for (int ni = 0; ni < NFRAG; ++ni)
#pragma unroll
      for (int ks = 0; ks < 2; ++ks)
        bfrag[ni][ks] = rdB(t, ni, ks);
#pragma unroll
    for (int j = 0; j < 2; ++j)
#pragma unroll
      for (int ks = 0; ks < 2; ++ks)
        afrag[j][ks] = rdA(t, j, ks);
    if (t + 1 < NT) { stageA(t + 1, 0); stageA(t + 1, 1); stageA(t + 1, 2); stageA(t + 1, 3); }
    SCHED0();
    BARRIER();
    __builtin_amdgcn_s_setprio(1);
#pragma unroll
    for (int j = 0; j < 2; ++j)
#pragma unroll
      for (int ni = 0; ni < NFRAG; ++ni)
#pragma unroll
        for (int ks = 0; ks < 2; ++ks)
          acc[j][ni] = mfma16(afrag[j][ks], bfrag[ni][ks], acc[j][ni]);
    __builtin_amdgcn_s_setprio(0);
    SCHED0();
    BARRIER();
    // ---- P2: issue A(t) mi23 reads; stage B(t+2); counted vmcnt; MFMA mi=2,3
#pragma unroll
    for (int j = 0; j < 2; ++j)
#pragma unroll
      for (int ks = 0; ks < 2; ++ks)
        afrag[j][ks] = rdA(t, 2 + j, ks);
    if (t + 2 < NT) {
#pragma unroll
      for (int u = 0; u < BU; ++u) stageB(t + 2, u);
    }
    SCHED0();
    BARRIER();
    if (t < NT - 2) {
      if constexpr (BU == 6) { VMCNT(6); } else { VMCNT(4); }
    } else if (t == NT - 2) {
      VMCNT(0);
    }
    __builtin_amdgcn_s_setprio(1);
#pragma unroll
    for (int j = 0; j < 2; ++j)
#pragma unroll
      for (int ni = 0; ni < NFRAG; ++ni)
#pragma unroll
        for (int ks = 0; ks < 2; ++ks)
          acc[2 + j][ni] = mfma16(afrag[j][ks], bfrag[ni][ks], acc[2 + j][ni]);
    __builtin_amdgcn_s_setprio(0);
    SCHED0();
    BARRIER();
  }

  if (MODE == 0) {
#pragma unroll
    for (int ni = 0; ni < NFRAG; ++ni) {
      const int cg = bcol + wn * (BN / 2) + ni * 16 + lo;
      const int chunk = cg >> 7;
      const int slot = chunk % 3, head = chunk / 3;
      bf16_t* dst = (slot == 0) ? q_out : (slot == 1) ? k_out : v_out;
      dst += (size_t)head * S_LEN * HD;
      const float scale = (slot == 0) ? INV_NORM : 1.0f;
      const float bb = bias[cg];
      const int d = cg & 127;
#pragma unroll
      for (int mi = 0; mi < 4; ++mi) {
#pragma unroll
        for (int jj = 0; jj < 4; ++jj) {
          const int r = brow + wm * 64 + mi * 16 + g * 4 + jj;
          dst[(size_t)r * HD + d] = (bf16_t)((acc[mi][ni][jj] + bb) * scale);
        }
      }
    }
  } else {
#pragma unroll
    for (int ni = 0; ni < NFRAG; ++ni) {
      const int cg = bcol + wn * (BN / 2) + ni * 16 + lo;
      const float bb = bias[cg];
#pragma unroll
      for (int mi = 0; mi < 4; ++mi) {
#pragma unroll
        for (int jj = 0; jj < 4; ++jj) {
          const int r = brow + wm * 64 + mi * 16 + g * 4 + jj;
          f_out[(size_t)r * H_DIM + cg] = acc[mi][ni][jj] + bb + residual[(size_t)r * H_DIM + cg];
        }
      }
    }
  }
}

// ---------------- Flash attention w/ ALiBi + causal mask (pipelined v2) ----------------
// (unchanged from round 8 — passed, ~105us est.)
__global__ __launch_bounds__(256, 2)
void attn_kernel(const bf16_t* __restrict__ Qg,
                 const bf16_t* __restrict__ Kg,
                 const bf16_t* __restrict__ Vg,
                 const float* __restrict__ alibi,
                 bf16_t* __restrict__ ctx)
{
  const int bid = blockIdx.x;
  const int h  = (bid & 7) * 4 + ((bid >> 3) & 3);
  const int qb = 31 - (bid >> 5);
  const int tid = threadIdx.x, lane = tid & 63, w = tid >> 6;
  const int lo = lane & 15, g = lane >> 4;

  __shared__ __align__(16) bf16_t Ks[2][64 * 128];  // SWZ256 [kv][128], 32KB
  __shared__ bf16_t Vt[2][128][72];                 // [d][kv] pad72, 36KB
  __shared__ bf16_t Pl[4][16][72];                  // per-wave P [q][kv], 9KB

  const bf16_t* Qh = Qg + ((size_t)h * S_LEN + qb * 64 + w * 16) * HD;
  const bf16_t* Kh = Kg + (size_t)h * S_LEN * HD;
  const bf16_t* Vh = Vg + (size_t)h * S_LEN * HD;
  const float slope = alibi[(size_t)h * S_LEN + 1];  // alibi[h][0][1] == slope (fp32-exact)

  bf16x8 qf[4];
#pragma unroll
  for (int ds = 0; ds < 4; ds++)
    qf[ds] = *(const bf16x8*)(Qh + lo * HD + ds * 32 + g * 8);

  f32x4 oacc[8] = {};
  float m_r[4], l_r[4];
#pragma unroll
  for (int jj = 0; jj < 4; jj++) { m_r[jj] = -INFINITY; l_r[jj] = 0.f; }

  const int ntiles = qb + 1;
  const int q_base = qb * 64 + w * 16;

  // ---- prologue: vv(0) loads, then K(0) async stage  [FIFO: vv x4, K x4]
  bf16x8 vvA[4], vvB[4];
#pragma unroll
  for (int u = 0; u < 4; ++u)
    vvA[u] = *(const bf16x8*)(Vh + (size_t)lane * HD + (u * 4 + w) * 8);
#pragma unroll
  for (int u = 0; u < 4; ++u) {
    const int lin = u * 4096 + tid * 16;
    const int lg = SWZ256(lin);
    async16(Kh + (size_t)(lg >> 8) * HD + ((lg & 255) >> 1),
            (char*)&Ks[0][0] + u * 4096 + w * 1024);
  }

  for (int kt = 0; kt < ntiles; ++kt) {
    const int k0 = kt * 64;
    const int cur = kt & 1;
    const bf16x8* vvC = cur ? vvB : vvA;
    bf16x8* vvN = cur ? vvA : vvB;

    // ---- write V^T[cur] from regs (compiler inserts tight vmcnt for vvC)
#pragma unroll
    for (int u = 0; u < 4; ++u) {
      const int d0 = (u * 4 + w) * 8;
#pragma unroll
      for (int e = 0; e < 8; ++e) Vt[cur][d0 + e][lane] = vvC[u][e];
    }
    // ---- prefetch V(kt+1) into the other reg set
    if (kt + 1 < ntiles) {
      const bf16_t* Vn = Vh + (size_t)(k0 + 64) * HD;
#pragma unroll
      for (int u = 0; u < 4; ++u)
        vvN[u] = *(const bf16x8*)(Vn + (size_t)lane * HD + (u * 4 + w) * 8);
    }
    SCHED0();
    if (kt + 1 < ntiles) { VMCNT(4); } else { VMCNT(0); }   // K(kt) staged in Ks[cur]
    LGKM0();                                                 // Vt[cur] writes drained
    SCHED0();
    BARRIER();
    SCHED0();
    // ---- issue K(kt+1) async stage into the other buffer
    if (kt + 1 < ntiles) {
      const bf16_t* Kn = Kh + (size_t)(k0 + 64) * HD;
#pragma unroll
      for (int u = 0; u < 4; ++u) {
        const int lin = u * 4096 + tid * 16;
        const int lg = SWZ256(lin);
        async16(Kn + (size_t)(lg >> 8) * HD + ((lg & 255) >> 1),
                (char*)&Ks[cur ^ 1][0] + u * 4096 + w * 1024);
      }
    }

    // ---- QK^T from LDS (swizzled reads; compiler schedules lgkmcnt)
    f32x4 sacc[4] = {};
#pragma unroll
    for (int kc = 0; kc < 4; ++kc) {
      bf16x8 kf[4];
#pragma unroll
      for (int ds = 0; ds < 4; ++ds) {
        const int lin = (kc * 16 + lo) * 256 + ds * 64 + g * 16;
        kf[ds] = *(const bf16x8*)((const char*)&Ks[cur][0] + SWZ256(lin));
      }
      __builtin_amdgcn_s_setprio(1);
#pragma unroll
      for (int ds = 0; ds < 4; ++ds)
        sacc[kc] = mfma16(qf[ds], kf[ds], sacc[kc]);
      __builtin_amdgcn_s_setprio(0);
    }

    // ---- scores = qk + slope*k (bit-exact alibi), causal mask on diagonal tile
    float sv[4][4];
#pragma unroll
    for (int kc = 0; kc < 4; kc++) {
      const float alk = slope * (float)(k0 + kc * 16 + lo);
#pragma unroll
      for (int jj = 0; jj < 4; jj++)
        sv[kc][jj] = sacc[kc][jj] + alk;
    }
    if (kt == ntiles - 1) {
#pragma unroll
      for (int kc = 0; kc < 4; kc++) {
        const int k_gl = k0 + kc * 16 + lo;
#pragma unroll
        for (int jj = 0; jj < 4; jj++) {
          const int q_gl = q_base + g * 4 + jj;
          if (k_gl > q_gl) sv[kc][jj] = -INFINITY;
        }
      }
    }

    // ---- online softmax (row = g*4+jj, cols across lane&15)
#pragma unroll
    for (int jj = 0; jj < 4; jj++) {
      float mx = fmaxf(fmaxf(sv[0][jj], sv[1][jj]), fmaxf(sv[2][jj], sv[3][jj]));
      mx = fmaxf(mx, __shfl_xor(mx, 1, 64));
      mx = fmaxf(mx, __shfl_xor(mx, 2, 64));
      mx = fmaxf(mx, __shfl_xor(mx, 4, 64));
      mx = fmaxf(mx, __shfl_xor(mx, 8, 64));
      const float mn = fmaxf(m_r[jj], mx);
      const float sc = __expf(m_r[jj] - mn);
      m_r[jj] = mn;
      l_r[jj] *= sc;
#pragma unroll
      for (int df = 0; df < 8; df++) oacc[df][jj] *= sc;
      float rs = 0.f;
#pragma unroll
      for (int kc = 0; kc < 4; kc++) {
        const float p = __expf(sv[kc][jj] - mn);
        rs += p;
        Pl[w][g * 4 + jj][kc * 16 + lo] = (bf16_t)p;
      }
      rs += __shfl_xor(rs, 1, 64);
      rs += __shfl_xor(rs, 2, 64);
      rs += __shfl_xor(rs, 4, 64);
      rs += __shfl_xor(rs, 8, 64);
      l_r[jj] += rs;
    }

    // ---- PV: oacc += P(16x64) * V^T[cur]  (same-wave Pl RAW: compiler-tracked)
#pragma unroll
    for (int ks = 0; ks < 2; ++ks) {
      bf16x8 pa = *(const bf16x8*)&Pl[w][lo][ks * 32 + g * 8];
#pragma unroll
      for (int df = 0; df < 8; df++) {
        bf16x8 vf = *(const bf16x8*)&Vt[cur][df * 16 + lo][ks * 32 + g * 8];
        __builtin_amdgcn_s_setprio(1);
        oacc[df] = mfma16(pa, vf, oacc[df]);
        __builtin_amdgcn_s_setprio(0);
      }
    }
  }

  // ---- finalize: divide by l, write ctx [S][H] bf16
#pragma unroll
  for (int jj = 0; jj < 4; jj++) {
    const float inv = 1.0f / l_r[jj];
    const int r = q_base + g * 4 + jj;
#pragma unroll
    for (int df = 0; df < 8; df++) {
      const int d = df * 16 + lo;
      ctx[(size_t)r * H_DIM + h * HD + d] = (bf16_t)(oacc[df][jj] * inv);
    }
  }
}

// ---------------- launch ----------------
extern "C" void kernel_launch(void* const* d_in, const int* in_sizes, int n_in,
                              void* d_out, int out_size, void* d_ws, size_t ws_size,
                              hipStream_t stream) {
  const float* hidden   = (const float*)d_in[0];
  const float* residual = (const float*)d_in[1];
  const float* alibi    = (const float*)d_in[2];
  // d_in[3] attention_mask: analytic (triu k=1 == causal), unused
  const float* w_qkv    = (const float*)d_in[4];
  const float* b_qkv    = (const float*)d_in[5];
  const float* w_dense  = (const float*)d_in[6];
  const float* b_dense  = (const float*)d_in[7];
  float* out = (float*)d_out;

  char* ws = (char*)d_ws;
  bf16_t* Xb  = (bf16_t*)(ws);                 // 2048*4096*2      = 16,777,216
  bf16_t* Wqb = (bf16_t*)(ws + 16777216);      // 12288*4096*2     = 100,663,296
  bf16_t* Wdb = (bf16_t*)(ws + 117440512);     // 4096*4096*2      = 33,554,432
  bf16_t* Qb  = (bf16_t*)(ws + 150994944);     // 32*2048*128*2    = 16,777,216
  bf16_t* Kb  = (bf16_t*)(ws + 167772160);
  bf16_t* Vb  = (bf16_t*)(ws + 184549376);
  bf16_t* Ctx = (bf16_t*)(ws + 201326592);

  // fp32 -> bf16 converts, single launch (BW-bound)
  {
    int n4 = NX4 + NQ4 + ND4;   // 18,874,368
    cvt_all<<<(n4 + 255) / 256, 256, 0, stream>>>(hidden, w_qkv, w_dense, Xb, Wqb, Wdb);
  }

  // QKV GEMM (128x192, 2 blocks/CU): grid 64 x 16 = 1024 blocks = 2 exact rounds
  gemm_pipe<0, 192><<<dim3(N_QKV / 192, S_LEN / 128), 256, 0, stream>>>(
      Xb, Wqb, b_qkv, nullptr, Qb, Kb, Vb, nullptr, N_QKV / 192);

  // attention (pipelined v2)
  attn_kernel<<<NHEAD * (S_LEN / 64), 256, 0, stream>>>(Qb, Kb, Vb, alibi, Ctx);

  // dense GEMM (128x128, 2 blocks/CU): grid 32 x 16 = 512 blocks = 1 exact round
  gemm_pipe<1, 128><<<dim3(H_DIM / 128, S_LEN / 128), 256, 0, stream>>>(
      Ctx, Wdb, b_dense, residual, nullptr, nullptr, nullptr, out, H_DIM / 128);
}

// Round 13
// 448.181 us; speedup vs baseline: 1.1434x; 1.1434x over previous
//
#include <hip/hip_runtime.h>
#include <cstdint>
#include <cstddef>

#define S_LEN 2048
#define H_DIM 4096
#define NHEAD 32
#define HD    128
#define N_QKV 12288
#define INV_NORM 0.08838834764831845f  // 1/sqrt(128)

typedef __bf16 bf16_t;
typedef bf16_t bf16x8 __attribute__((ext_vector_type(8)));
typedef bf16_t bf16x4 __attribute__((ext_vector_type(4)));
typedef float  f32x4  __attribute__((ext_vector_type(4)));

static_assert(sizeof(bf16x8) == 16, "bf16x8 must be 16B");

__device__ __forceinline__ f32x4 mfma16(bf16x8 a, bf16x8 b, f32x4 c) {
  return __builtin_amdgcn_mfma_f32_16x16x32_bf16(a, b, c, 0, 0, 0);
}

// async global->LDS, 16B per lane. LDS dest must be wave-uniform base; HW adds lane*16.
typedef __attribute__((address_space(1))) void gas_void;
typedef __attribute__((address_space(3))) void las_void;
__device__ __forceinline__ void async16(const void* g, void* l) {
  __builtin_amdgcn_global_load_lds((const gas_void*)g,
                                   (las_void*)(uint32_t)(uintptr_t)l,
                                   16, 0, 0);
}

// 3-bit row XOR swizzle (G4): byte ^= (row&7)<<4.
// SWZ   : 128B rows (row = byte>>7) — GEMM tiles
// SWZ256: 256B rows (row = byte>>8) — attention K tiles (HD=128 bf16 rows)
// Both: involution, preserves 16B granules, spreads 16-lane column reads over 8 bank-quads.
#define SWZ(x)    ((x) ^ ((((x) >> 7) & 7) << 4))
#define SWZ256(x) ((x) ^ ((((x) >> 8) & 7) << 4))
#define VMCNT(n) asm volatile("s_waitcnt vmcnt(" #n ")" ::: "memory")
#define LGKM0()  asm volatile("s_waitcnt lgkmcnt(0)" ::: "memory")
#define SCHED0() __builtin_amdgcn_sched_barrier(0)
#define BARRIER() __builtin_amdgcn_s_barrier()

// ---------------- fp32 -> bf16 conversion: all three tensors in one launch ----------------
typedef float f32v4 __attribute__((ext_vector_type(4)));
#define NX4 ((S_LEN * H_DIM) / 4)
#define NQ4 ((N_QKV * H_DIM) / 4)
#define ND4 ((H_DIM * H_DIM) / 4)
__global__ void cvt_all(const float* __restrict__ x, const float* __restrict__ wq,
                        const float* __restrict__ wd,
                        bf16_t* __restrict__ xb, bf16_t* __restrict__ wqb,
                        bf16_t* __restrict__ wdb) {
  int i = blockIdx.x * 256 + threadIdx.x;
  const float* src; bf16_t* dst; int j;
  if (i < NX4) { src = x; dst = xb; j = i; }
  else if (i < NX4 + NQ4) { src = wq; dst = wqb; j = i - NX4; }
  else if (i < NX4 + NQ4 + ND4) { src = wd; dst = wdb; j = i - NX4 - NQ4; }
  else return;
  f32v4 v = ((const f32v4*)src)[j];
  bf16x4 r;
  r[0] = (bf16_t)v[0]; r[1] = (bf16_t)v[1]; r[2] = (bf16_t)v[2]; r[3] = (bf16_t)v[3];
  ((bf16x4*)dst)[j] = r;
}

// ============ GEMM template: 256 x BN tile, BK=64, 2-phase pipelined (r11, proven) ============
// C = A(Mx4096) * B(Nx4096)^T. 512 threads = 8 waves (4M x 2N); wave tile 64 x BN/2,
// acc[4][BN/32] f32x4. LDS: A 2buf x 32KB + B 2buf x BN*128B. Row-swizzled (SWZ) via
// inverse-swizzled global source (linear gload_lds dest) + swizzled ds_read.
//   P1: read B(t) all + A(t) chunks01; stage A(t+1) u0-u3; MFMA c=0,1
//   P2: read A(t) chunks23;            stage B(t+2) u0..;  vmcnt(NBU); MFMA c=2,3
// vmcnt FIFO ledger (verified by induction):
//   At P2(t) wait: FIFO = [B(t+1)xNBU, A(t+1)x4, B(t+2)xNBU] -> vmcnt(NBU) lands
//   B(t+1)+A(t+1). t==NT-2 -> VMCNT(0); t==NT-1 -> none.
//   Prologue FIFO [B0xNBU, A0x4, B1xNBU] -> vmcnt(NBU).
// MODE 0: QKV epilogue (scatter Q*INV_NORM / K / V per 128-col chunk)
// MODE 1: dense epilogue (fp32 out = acc + bias + residual)
template <int MODE, int BN>
__global__ __launch_bounds__(512, 2)
void gemm_pipe(const bf16_t* __restrict__ Ag,
               const bf16_t* __restrict__ Bg,
               const float* __restrict__ bias,
               const float* __restrict__ residual,
               bf16_t* __restrict__ q_out,
               bf16_t* __restrict__ k_out,
               bf16_t* __restrict__ v_out,
               float* __restrict__ f_out,
               int ncol)
{
  constexpr int NFRAG = BN / 32;      // B col-frags per wave (16 cols each)
  constexpr int NBU   = BN / 64;      // B stage units (8KB each)
  constexpr int BBUF  = BN * 128;     // B bytes per buffer
  __shared__ __align__(16) char sm[65536 + 2 * BBUF];
  char* smA = sm;             // [buf][32768]
  char* smB = sm + 65536;     // [buf][BBUF]
  const int Kdim = H_DIM;
  const int NT = Kdim >> 6;   // 64 K-tiles

  const int tid = threadIdx.x, lane = tid & 63, w = tid >> 6;
  const int wm = w >> 1, wn = w & 1;
  const int lo = lane & 15, g = lane >> 4;

  // XCD-aware bijective swizzle (nwg % 8 == 0)
  const int nwg = gridDim.x * gridDim.y;
  const int bid = blockIdx.y * gridDim.x + blockIdx.x;
  const int cpx = nwg >> 3;
  const int sbid = (bid & 7) * cpx + (bid >> 3);
  const int brow = (sbid / ncol) << 8;
  const int bcol = (sbid % ncol) * BN;

  auto stageA = [&](int t, int u) {          // u = 0..3, 8KB each
    const int lin = u * 8192 + w * 1024 + lane * 16;
    const int lg = SWZ(lin);
    const bf16_t* src = Ag + (size_t)(brow + (lg >> 7)) * Kdim + (t << 6) + ((lg & 127) >> 1);
    async16(src, smA + ((t & 1) * 32768 + u * 8192 + w * 1024));
  };
  auto stageB = [&](int t, int u) {          // u = 0..NBU-1
    const int lin = u * 8192 + w * 1024 + lane * 16;
    const int lg = SWZ(lin);
    const bf16_t* src = Bg + (size_t)(bcol + (lg >> 7)) * Kdim + (t << 6) + ((lg & 127) >> 1);
    async16(src, smB + ((t & 1) * BBUF + u * 8192 + w * 1024));
  };
  auto rdA = [&](int t, int mi, int ks) -> bf16x8 {
    const int lin = (wm * 64 + mi * 16 + lo) * 128 + ks * 64 + g * 16;
    return *(const bf16x8*)(smA + (t & 1) * 32768 + SWZ(lin));
  };
  auto rdB = [&](int t, int ni, int ks) -> bf16x8 {
    const int lin = (wn * (BN / 2) + ni * 16 + lo) * 128 + ks * 64 + g * 16;
    return *(const bf16x8*)(smB + (t & 1) * BBUF + SWZ(lin));
  };

  f32x4 acc[4][NFRAG] = {};
  bf16x8 bfrag[NFRAG][2];

  // ---- prologue
#pragma unroll
  for (int u = 0; u < NBU; ++u) stageB(0, u);
  stageA(0, 0); stageA(0, 1); stageA(0, 2); stageA(0, 3);
#pragma unroll
  for (int u = 0; u < NBU; ++u) stageB(1, u);
  if constexpr (NBU == 3) { VMCNT(3); } else { VMCNT(2); }
  SCHED0();
  BARRIER();

  for (int t = 0; t < NT; ++t) {
    bf16x8 afrag[2][2];
    // ---- P1: issue B(t) all + A(t) chunks01 reads; stage A(t+1)
#pragma unroll
    for (int ni = 0; ni < NFRAG; ++ni)
#pragma unroll
      for (int ks = 0; ks < 2; ++ks)
        bfrag[ni][ks] = rdB(t, ni, ks);
#pragma unroll
    for (int j = 0; j < 2; ++j)
#pragma unroll
      for (int ks = 0; ks < 2; ++ks)
        afrag[j][ks] = rdA(t, j, ks);
    if (t + 1 < NT) { stageA(t + 1, 0); stageA(t + 1, 1); stageA(t + 1, 2); stageA(t + 1, 3); }
    SCHED0();
    BARRIER();
    __builtin_amdgcn_s_setprio(1);
#pragma unroll
    for (int j = 0; j < 2; ++j)
#pragma unroll
      for (int ni = 0; ni < NFRAG; ++ni)
#pragma unroll
        for (int ks = 0; ks < 2; ++ks)
          acc[j][ni] = mfma16(afrag[j][ks], bfrag[ni][ks], acc[j][ni]);
    __builtin_amdgcn_s_setprio(0);
    SCHED0();
    BARRIER();
    // ---- P2: issue A(t) chunks23 reads; stage B(t+2); counted vmcnt; MFMA c23
#pragma unroll
    for (int j = 0; j < 2; ++j)
#pragma unroll
      for (int ks = 0; ks < 2; ++ks)
        afrag[j][ks] = rdA(t, 2 + j, ks);
    if (t + 2 < NT) {
#pragma unroll
      for (int u = 0; u < NBU; ++u) stageB(t + 2, u);
    }
    SCHED0();
    BARRIER();
    if (t < NT - 2) {
      if constexpr (NBU == 3) { VMCNT(3); } else { VMCNT(2); }
    } else if (t == NT - 2) {
      VMCNT(0);
    }
    __builtin_amdgcn_s_setprio(1);
#pragma unroll
    for (int j = 0; j < 2; ++j)
#pragma unroll
      for (int ni = 0; ni < NFRAG; ++ni)
#pragma unroll
        for (int ks = 0; ks < 2; ++ks)
          acc[2 + j][ni] = mfma16(afrag[j][ks], bfrag[ni][ks], acc[2 + j][ni]);
    __builtin_amdgcn_s_setprio(0);
    SCHED0();
    BARRIER();
  }

  if (MODE == 0) {
#pragma unroll
    for (int ni = 0; ni < NFRAG; ++ni) {
      const int cg = bcol + wn * (BN / 2) + ni * 16 + lo;
      const int chunk = cg >> 7;
      const int slot = chunk % 3, head = chunk / 3;
      bf16_t* dst = (slot == 0) ? q_out : (slot == 1) ? k_out : v_out;
      dst += (size_t)head * S_LEN * HD;
      const float scale = (slot == 0) ? INV_NORM : 1.0f;
      const float bb = bias[cg];
      const int d = cg & 127;
#pragma unroll
      for (int mi = 0; mi < 4; ++mi) {
#pragma unroll
        for (int jj = 0; jj < 4; ++jj) {
          const int r = brow + wm * 64 + mi * 16 + g * 4 + jj;
          dst[(size_t)r * HD + d] = (bf16_t)((acc[mi][ni][jj] + bb) * scale);
        }
      }
    }
  } else {
#pragma unroll
    for (int ni = 0; ni < NFRAG; ++ni) {
      const int cg = bcol + wn * (BN / 2) + ni * 16 + lo;
      const float bb = bias[cg];
#pragma unroll
      for (int mi = 0; mi < 4; ++mi) {
#pragma unroll
        for (int jj = 0; jj < 4; ++jj) {
          const int r = brow + wm * 64 + mi * 16 + g * 4 + jj;
          f_out[(size_t)r * H_DIM + cg] = acc[mi][ni][jj] + bb + residual[(size_t)r * H_DIM + cg];
        }
      }
    }
  }
}

// ---------------- Flash attention w/ ALiBi + causal mask (pipelined v3) ----------------
// r13 changes vs r8: (1) l-sum via ones-column MFMA (oaccL) — removes 16 sum-shuffles
// per wave/tile; l extracted once at finalize via one shfl per row. (2) defer-max
// RESCALE_THRESHOLD=8 (T13): skip max-update+O-rescale when all rows grew <= 8;
// P bounded by e^8 (~3e3, bf16-safe; l <= 2048*e^8 ~ 6e6, f32-safe). (3) setprio
// hoisted to whole MFMA clusters.
__global__ __launch_bounds__(256, 2)
void attn_kernel(const bf16_t* __restrict__ Qg,
                 const bf16_t* __restrict__ Kg,
                 const bf16_t* __restrict__ Vg,
                 const float* __restrict__ alibi,
                 bf16_t* __restrict__ ctx)
{
  const int bid = blockIdx.x;
  const int h  = (bid & 7) * 4 + ((bid >> 3) & 3);
  const int qb = 31 - (bid >> 5);
  const int tid = threadIdx.x, lane = tid & 63, w = tid >> 6;
  const int lo = lane & 15, g = lane >> 4;

  __shared__ __align__(16) bf16_t Ks[2][64 * 128];  // SWZ256 [kv][128], 32KB
  __shared__ bf16_t Vt[2][128][72];                 // [d][kv] pad72, 36KB
  __shared__ bf16_t Pl[4][16][72];                  // per-wave P [q][kv], 9KB

  const bf16_t* Qh = Qg + ((size_t)h * S_LEN + qb * 64 + w * 16) * HD;
  const bf16_t* Kh = Kg + (size_t)h * S_LEN * HD;
  const bf16_t* Vh = Vg + (size_t)h * S_LEN * HD;
  const float slope = alibi[(size_t)h * S_LEN + 1];  // alibi[h][0][1] == slope (fp32-exact)

  bf16x8 qf[4];
#pragma unroll
  for (int ds = 0; ds < 4; ds++)
    qf[ds] = *(const bf16x8*)(Qh + lo * HD + ds * 32 + g * 8);

  // ones B-frag: output col 0 accumulates row-sum of P (the softmax denominator)
  bf16x8 vones;
#pragma unroll
  for (int e = 0; e < 8; ++e) vones[e] = (bf16_t)((lo == 0) ? 1.0f : 0.0f);

  f32x4 oacc[8] = {};
  f32x4 oaccL = {};
  float m_r[4];
#pragma unroll
  for (int jj = 0; jj < 4; jj++) m_r[jj] = -INFINITY;

  const int ntiles = qb + 1;
  const int q_base = qb * 64 + w * 16;

  // ---- prologue: vv(0) loads, then K(0) async stage  [FIFO: vv x4, K x4]
  bf16x8 vvA[4], vvB[4];
#pragma unroll
  for (int u = 0; u < 4; ++u)
    vvA[u] = *(const bf16x8*)(Vh + (size_t)lane * HD + (u * 4 + w) * 8);
#pragma unroll
  for (int u = 0; u < 4; ++u) {
    const int lin = u * 4096 + tid * 16;
    const int lg = SWZ256(lin);
    async16(Kh + (size_t)(lg >> 8) * HD + ((lg & 255) >> 1),
            (char*)&Ks[0][0] + u * 4096 + w * 1024);
  }

  for (int kt = 0; kt < ntiles; ++kt) {
    const int k0 = kt * 64;
    const int cur = kt & 1;
    const bf16x8* vvC = cur ? vvB : vvA;
    bf16x8* vvN = cur ? vvA : vvB;

    // ---- write V^T[cur] from regs (compiler inserts tight vmcnt for vvC)
#pragma unroll
    for (int u = 0; u < 4; ++u) {
      const int d0 = (u * 4 + w) * 8;
#pragma unroll
      for (int e = 0; e < 8; ++e) Vt[cur][d0 + e][lane] = vvC[u][e];
    }
    // ---- prefetch V(kt+1) into the other reg set
    if (kt + 1 < ntiles) {
      const bf16_t* Vn = Vh + (size_t)(k0 + 64) * HD;
#pragma unroll
      for (int u = 0; u < 4; ++u)
        vvN[u] = *(const bf16x8*)(Vn + (size_t)lane * HD + (u * 4 + w) * 8);
    }
    SCHED0();
    if (kt + 1 < ntiles) { VMCNT(4); } else { VMCNT(0); }   // K(kt) staged in Ks[cur]
    LGKM0();                                                 // Vt[cur] writes drained
    SCHED0();
    BARRIER();
    SCHED0();
    // ---- issue K(kt+1) async stage into the other buffer
    if (kt + 1 < ntiles) {
      const bf16_t* Kn = Kh + (size_t)(k0 + 64) * HD;
#pragma unroll
      for (int u = 0; u < 4; ++u) {
        const int lin = u * 4096 + tid * 16;
        const int lg = SWZ256(lin);
        async16(Kn + (size_t)(lg >> 8) * HD + ((lg & 255) >> 1),
                (char*)&Ks[cur ^ 1][0] + u * 4096 + w * 1024);
      }
    }

    // ---- QK^T from LDS (swizzled reads; compiler schedules lgkmcnt)
    f32x4 sacc[4] = {};
    __builtin_amdgcn_s_setprio(1);
#pragma unroll
    for (int kc = 0; kc < 4; ++kc) {
      bf16x8 kf[4];
#pragma unroll
      for (int ds = 0; ds < 4; ++ds) {
        const int lin = (kc * 16 + lo) * 256 + ds * 64 + g * 16;
        kf[ds] = *(const bf16x8*)((const char*)&Ks[cur][0] + SWZ256(lin));
      }
#pragma unroll
      for (int ds = 0; ds < 4; ++ds)
        sacc[kc] = mfma16(qf[ds], kf[ds], sacc[kc]);
    }
    __builtin_amdgcn_s_setprio(0);

    // ---- scores = qk + slope*k (bit-exact alibi), causal mask on diagonal tile
    float sv[4][4];
#pragma unroll
    for (int kc = 0; kc < 4; kc++) {
      const float alk = slope * (float)(k0 + kc * 16 + lo);
#pragma unroll
      for (int jj = 0; jj < 4; jj++)
        sv[kc][jj] = sacc[kc][jj] + alk;
    }
    if (kt == ntiles - 1) {
#pragma unroll
      for (int kc = 0; kc < 4; kc++) {
        const int k_gl = k0 + kc * 16 + lo;
#pragma unroll
        for (int jj = 0; jj < 4; jj++) {
          const int q_gl = q_base + g * 4 + jj;
          if (k_gl > q_gl) sv[kc][jj] = -INFINITY;
        }
      }
    }

    // ---- online softmax: row max (row = g*4+jj, cols across lane&15)
    float mx[4];
#pragma unroll
    for (int jj = 0; jj < 4; jj++) {
      float m0 = fmaxf(fmaxf(sv[0][jj], sv[1][jj]), fmaxf(sv[2][jj], sv[3][jj]));
      m0 = fmaxf(m0, __shfl_xor(m0, 1, 64));
      m0 = fmaxf(m0, __shfl_xor(m0, 2, 64));
      m0 = fmaxf(m0, __shfl_xor(m0, 4, 64));
      m0 = fmaxf(m0, __shfl_xor(m0, 8, 64));
      mx[jj] = m0;
    }
    // ---- defer-max (T13): rescale only if some row grew > THR
    bool need = false;
#pragma unroll
    for (int jj = 0; jj < 4; jj++) need = need || (mx[jj] > m_r[jj] + 8.0f);
    if (__any(need)) {
#pragma unroll
      for (int jj = 0; jj < 4; jj++) {
        const float mn = fmaxf(m_r[jj], mx[jj]);
        const float sc = __expf(m_r[jj] - mn);
        m_r[jj] = mn;
#pragma unroll
        for (int df = 0; df < 8; df++) oacc[df][jj] *= sc;
        oaccL[jj] *= sc;
      }
    }
    // ---- P = exp(S - m), write to per-wave LDS (row-sum comes from ones-MFMA)
#pragma unroll
    for (int jj = 0; jj < 4; jj++)
#pragma unroll
      for (int kc = 0; kc < 4; kc++)
        Pl[w][g * 4 + jj][kc * 16 + lo] = (bf16_t)__expf(sv[kc][jj] - m_r[jj]);

    // ---- PV: oacc += P(16x64) * V^T[cur]; oaccL += P * ones (denominator)
    __builtin_amdgcn_s_setprio(1);
#pragma unroll
    for (int ks = 0; ks < 2; ++ks) {
      bf16x8 pa = *(const bf16x8*)&Pl[w][lo][ks * 32 + g * 8];
      oaccL = mfma16(pa, vones, oaccL);
#pragma unroll
      for (int df = 0; df < 8; df++) {
        bf16x8 vf = *(const bf16x8*)&Vt[cur][df * 16 + lo][ks * 32 + g * 8];
        oacc[df] = mfma16(pa, vf, oacc[df]);
      }
    }
    __builtin_amdgcn_s_setprio(0);
  }

  // ---- finalize: l = oaccL broadcast from col-0 lane of each row group
#pragma unroll
  for (int jj = 0; jj < 4; jj++) {
    const float l = __shfl(oaccL[jj], lane & 48, 64);
    const float inv = 1.0f / l;
    const int r = q_base + g * 4 + jj;
#pragma unroll
    for (int df = 0; df < 8; df++) {
      const int d = df * 16 + lo;
      ctx[(size_t)r * H_DIM + h * HD + d] = (bf16_t)(oacc[df][jj] * inv);
    }
  }
}

// ---------------- launch ----------------
extern "C" void kernel_launch(void* const* d_in, const int* in_sizes, int n_in,
                              void* d_out, int out_size, void* d_ws, size_t ws_size,
                              hipStream_t stream) {
  const float* hidden   = (const float*)d_in[0];
  const float* residual = (const float*)d_in[1];
  const float* alibi    = (const float*)d_in[2];
  // d_in[3] attention_mask: analytic (triu k=1 == causal), unused
  const float* w_qkv    = (const float*)d_in[4];
  const float* b_qkv    = (const float*)d_in[5];
  const float* w_dense  = (const float*)d_in[6];
  const float* b_dense  = (const float*)d_in[7];
  float* out = (float*)d_out;

  char* ws = (char*)d_ws;
  bf16_t* Xb  = (bf16_t*)(ws);                 // 2048*4096*2      = 16,777,216
  bf16_t* Wqb = (bf16_t*)(ws + 16777216);      // 12288*4096*2     = 100,663,296
  bf16_t* Wdb = (bf16_t*)(ws + 117440512);     // 4096*4096*2      = 33,554,432
  bf16_t* Qb  = (bf16_t*)(ws + 150994944);     // 32*2048*128*2    = 16,777,216
  bf16_t* Kb  = (bf16_t*)(ws + 167772160);
  bf16_t* Vb  = (bf16_t*)(ws + 184549376);
  bf16_t* Ctx = (bf16_t*)(ws + 201326592);

  // fp32 -> bf16 converts, single launch (BW-bound)
  {
    int n4 = NX4 + NQ4 + ND4;   // 18,874,368
    cvt_all<<<(n4 + 255) / 256, 256, 0, stream>>>(hidden, w_qkv, w_dense, Xb, Wqb, Wdb);
  }

  // QKV GEMM (256x192 2-phase): grid 64 x 8 = 512 blocks = 2 exact rounds
  gemm_pipe<0, 192><<<dim3(N_QKV / 192, S_LEN / 256), 512, 0, stream>>>(
      Xb, Wqb, b_qkv, nullptr, Qb, Kb, Vb, nullptr, N_QKV / 192);

  // attention (pipelined v3)
  attn_kernel<<<NHEAD * (S_LEN / 64), 256, 0, stream>>>(Qb, Kb, Vb, alibi, Ctx);

  // dense GEMM (256x128 2-phase): grid 32 x 8 = 256 blocks = 1 exact round
  gemm_pipe<1, 128><<<dim3(H_DIM / 128, S_LEN / 256), 512, 0, stream>>>(
      Ctx, Wdb, b_dense, residual, nullptr, nullptr, nullptr, out, H_DIM / 128);
}